// Round 11
// baseline (285.969 us; speedup 1.0000x reference)
//
#include <hip/hip_runtime.h>
#include <hip/hip_bf16.h>

typedef __hip_bfloat16 bf16;
typedef float f32x4 __attribute__((ext_vector_type(4)));
typedef short s16x8 __attribute__((ext_vector_type(8)));

#define B_    8
#define LP    12
#define NC    4096
#define NO    128
#define NAPO  8
#define NN    4224
#define E_    64
#define A_    64
#define H_    256
#define QC    80
#define PROJ0 65
#define NCHUNK 17

#define TOT_IN 688896
#define QTF_C  67584     // 132*512 shorts per (b,c) group
#define QTF_B  337920    // 5*QTF_C per batch
#define TB_P   983040    // dwords per kh-partial: 96*4*2560

struct Ptr16 { const void* p[16]; };
union U8 { s16x8 v; unsigned u[4]; };

__device__ __forceinline__ float b2f(bf16 x){ return __bfloat162float(x); }
__device__ __forceinline__ float bs2f(unsigned short s){
  union { unsigned u; float f; } x; x.u = ((unsigned)s) << 16; return x.f;
}
__device__ __forceinline__ unsigned short f2bs(float f){
  bf16 h = __float2bfloat16(f);
  union { bf16 h; unsigned short s; } x; x.h = h; return x.s;
}
__device__ __forceinline__ unsigned pack2(float a, float b){
  return (unsigned)f2bs(a) | ((unsigned)f2bs(b) << 16);
}
__device__ __forceinline__ float lo16f(unsigned w){
  union { unsigned u; float f; } x; x.u = w << 16; return x.f;
}
__device__ __forceinline__ float hi16f(unsigned w){
  union { unsigned u; float f; } x; x.u = w & 0xffff0000u; return x.f;
}
__device__ __forceinline__ float rdval(const void* p, int i, int fl){
  return fl ? ((const float*)p)[i] : bs2f(((const unsigned short*)p)[i]);
}

// accumulator block layout (floats, after qsum): esum[8] | cnt[8] | csumIn[64] | csumOut[64]
//                                                | objsumIn[512] | objsumOut[512]   (1168 total)

// ---------------- k_prep: detect + convert(2691) + awFrag(64) + obj+objsum(256) + csum(32) ----------------
__global__ void k_prep(Ptr16 ps, int* flag, float* dst,
                       unsigned short* awFrag,
                       const int* gtc, const int* gta,
                       float* objIn, float* objOut, float* qsum){
  int tid = threadIdx.x;
  // wave-local dtype detect: probe concept_embIn half-words; fp32 garbage -> ~46% exp>=137
  const unsigned short* u = (const unsigned short*)ps.p[4];
  int hit = (((u[tid*16] >> 7) & 0xFF) >= 137) ? 1 : 0;
  unsigned long long m = __ballot(hit);
  int fl = (m != 0ULL) ? 1 : 0;
  int mb = blockIdx.x;
  float* acc = qsum + 640;
  if (mb < 2691){
    int idx = mb*256 + tid;
    if (idx >= TOT_IN) return;
    constexpr int cum[17] = {0,16384,32768,49152,65536,327680,589824,589888,589952,
                             622720,622976,639360,639424,672192,672448,688832,688896};
    int t = 0;
    #pragma unroll
    for (int i=1;i<16;i++) if (idx >= cum[i]) t = i;
    dst[idx] = rdval(ps.p[t], idx - cum[t], fl);
  } else if (mb < 2755){
    int idx = (mb-2691)*256 + tid;              // < 16384
    int j = idx & 7;
    int lane = (idx >> 3) & 63;
    int mm = (idx >> 9) & 15;
    int kc = idx >> 13;
    int e = kc*32 + (lane>>4)*8 + j;
    int h = mm*16 + (lane&15);
    awFrag[idx] = f2bs(rdval(ps.p[8], e*H_ + h, fl));
  } else if (mb < 3011){
    __shared__ float ls[128];
    if (tid < 128) ls[tid] = 0.f;
    __syncthreads();
    int idx = (mb-2755)*256 + tid;              // < 65536
    int e = idx & 63; int bo = idx >> 6;
    int cls = gtc[bo];
    float vi = rdval(ps.p[0], cls*E_ + e, fl);
    float vo = rdval(ps.p[1], cls*E_ + e, fl);
    const int* ga = gta + bo*NAPO;
    #pragma unroll
    for (int j=0;j<NAPO;j++){
      int at = ga[j];
      vi += rdval(ps.p[2], at*E_ + e, fl);
      vo += rdval(ps.p[3], at*E_ + e, fl);
    }
    objIn[idx] = vi; objOut[idx] = vo;
    atomicAdd(&ls[e], vi);
    atomicAdd(&ls[64+e], vo);
    __syncthreads();
    int b = (mb - 2755) >> 5;
    float* objsumIn  = acc + 144;
    float* objsumOut = acc + 656;
    if (tid < 64) atomicAdd(&objsumIn[b*64+tid], ls[tid]);
    else if (tid < 128) atomicAdd(&objsumOut[b*64+(tid-64)], ls[tid]);
  } else {
    // csum family: 32 blocks, colsums of conceptIn/conceptOut (raw inputs)
    int j = mb - 3011;
    __shared__ float ls[128];
    if (tid < 128) ls[tid] = 0.f;
    __syncthreads();
    int e = tid & 63, r0 = tid >> 6;
    float si = 0.f, so = 0.f;
    for (int rr = r0; rr < 128; rr += 4){
      int row = j*128 + rr;
      si += rdval(ps.p[4], row*E_ + e, fl);
      so += rdval(ps.p[5], row*E_ + e, fl);
    }
    atomicAdd(&ls[e], si);
    atomicAdd(&ls[64+e], so);
    __syncthreads();
    float* csumIn  = acc + 16;
    float* csumOut = acc + 80;
    if (tid < 64) atomicAdd(&csumIn[tid], ls[tid]);
    else if (tid < 128) atomicAdd(&csumOut[tid-64], ls[tid]);
    if (j == 0 && tid == 0) *flag = fl;
  }
}

// ================ k_mid: meta(8) | QTf(136) | baseT->Aopt(80) | qsum-finalize(8) ================
__device__ __forceinline__ void mid_meta(char* smem, int b,
                       const float* conceptOut, const float* meta_init,
                       const float* mw1, const float* mb1, const float* mw2, const float* mb2,
                       const float* aw1, const float* ab1,
                       const int* ops, const int* args,
                       float* metaAll, float* metaH){
  unsigned* mw1p = (unsigned*)smem;               // 64*256 = 65536 B
  unsigned* mw2p = (unsigned*)(smem + 65536);     // 128*64 = 32768 B
  unsigned* aw1p = (unsigned*)(smem + 98304);     // 32*256 = 32768 B
  float* meta_s  = (float*)(smem + 131072);
  float* argx    = (float*)(smem + 131328);
  float* hid     = (float*)(smem + 131584);
  float* part    = (float*)(smem + 132608);
  int tid = threadIdx.x;

  for (int i=tid; i<64*256; i+=256){
    int j2 = i >> 8, t = i & 255;
    mw1p[i] = pack2(mw1[(2*j2)*H_ + t], mw1[(2*j2+1)*H_ + t]);
  }
  for (int i=tid; i<128*64; i+=256){
    int h2 = i >> 6, a = i & 63;
    mw2p[i] = pack2(mw2[(2*h2)*A_ + a], mw2[(2*h2+1)*A_ + a]);
  }
  for (int i=tid; i<32*256; i+=256){
    int a2 = i >> 8, t = i & 255;
    aw1p[i] = pack2(aw1[(E_+2*a2)*H_ + t], aw1[(E_+2*a2+1)*H_ + t]);
  }
  float r_mb1 = mb1[tid];
  float r_ab1 = ab1[tid];
  float r_mb2 = (tid < A_) ? mb2[tid] : 0.f;
  if (tid < A_) meta_s[tid] = meta_init[tid];
  __syncthreads();

  for (int t=0;t<LP;t++){
    int op  = ops[b*LP + t];
    int arg = args[b*LP + t];
    if (tid >= 64 && tid < 128) argx[tid-64] = conceptOut[arg*E_ + (tid-64)];
    __syncthreads();
    float acc = r_mb1;
    for (int j2=0;j2<32;j2++){
      unsigned w = mw1p[j2*256 + tid];
      float2 xp = *(const float2*)&meta_s[2*j2];
      acc = fmaf(xp.x, lo16f(w), acc);
      acc = fmaf(xp.y, hi16f(w), acc);
    }
    for (int j2=0;j2<32;j2++){
      unsigned w = mw1p[(32+j2)*256 + tid];
      float2 xp = *(const float2*)&argx[2*j2];
      acc = fmaf(xp.x, lo16f(w), acc);
      acc = fmaf(xp.y, hi16f(w), acc);
    }
    hid[tid] = fmaxf(acc, 0.f);
    __syncthreads();
    int wv_ = tid >> 6, l = tid & 63;
    float acc2 = 0.f;
    for (int h2 = wv_*32; h2 < wv_*32+32; h2++){
      unsigned w = mw2p[h2*64 + l];
      float2 hp = *(const float2*)&hid[2*h2];
      acc2 = fmaf(hp.x, lo16f(w), acc2);
      acc2 = fmaf(hp.y, hi16f(w), acc2);
    }
    part[wv_*64 + l] = acc2;
    __syncthreads();
    if (tid < A_){
      float s = part[tid] + part[64+tid] + part[128+tid] + part[192+tid] + r_mb2;
      float nm = (op==0) ? s : meta_s[tid];
      meta_s[tid] = nm;
      metaAll[(b*LP+t)*A_ + tid] = nm;
    }
    __syncthreads();
    float mh = r_ab1;
    for (int a2=0;a2<32;a2++){
      unsigned w = aw1p[a2*256 + tid];
      float2 mp = *(const float2*)&meta_s[2*a2];
      mh = fmaf(mp.x, lo16f(w), mh);
      mh = fmaf(mp.y, hi16f(w), mh);
    }
    metaH[(b*LP+t)*H_ + tid] = mh;
  }
}

__device__ __forceinline__ void mid_qt(char* smem, int idx,
                       const float* conceptIn, const float* conceptOut, const int* args,
                       const float* objIn, const float* objOut,
                       unsigned short* QTf){
  float* tile = (float*)smem;                  // 256*65*4 = 66560 B
  float* argv = (float*)(smem + 66560);
  int b = idx / NCHUNK, chunk = idx % NCHUNK;
  int tid = threadIdx.x;
  int rows = (chunk < 16) ? 256 : 128;
  int n0 = chunk*256;
  int n = n0 + tid;
  bool valid = (tid < rows);
  unsigned short* Qb = QTf + (size_t)b*QTF_B + ((n>>5)*512 + (n&31));
  {
    const float* src = (chunk < 16) ? (conceptIn + (size_t)n0*E_) : (objIn + (size_t)b*NO*E_);
    int tot = rows*64;
    for (int i=tid; i<tot; i+=256) tile[(i>>6)*65 + (i&63)] = src[i];
  }
  __syncthreads();
  if (valid){
    Qb[0] = 0x3F80;
    Qb[4*QTF_C + 13*32] = 0;
    Qb[4*QTF_C + 14*32] = 0;
    Qb[4*QTF_C + 15*32] = 0;
    for (int e=0;e<64;e++){
      int qc = 1+e;
      Qb[(qc>>4)*QTF_C + (qc&15)*32] = f2bs(tile[tid*65 + e]);
    }
  }
  __syncthreads();
  for (int i=tid;i<LP*E_;i+=256) argv[i] = conceptOut[args[b*LP + (i>>6)]*E_ + (i&63)];
  {
    const float* src = (chunk < 16) ? (conceptOut + (size_t)n0*E_) : (objOut + (size_t)b*NO*E_);
    int tot = rows*64;
    for (int i=tid; i<tot; i+=256) tile[(i>>6)*65 + (i&63)] = src[i];
  }
  __syncthreads();
  if (valid){
    float dots[LP];
    #pragma unroll
    for (int t=0;t<LP;t++) dots[t] = 0.f;
    for (int e=0;e<64;e++){
      float o = tile[tid*65 + e];
      #pragma unroll
      for (int t=0;t<LP;t++) dots[t] += o*argv[t*64+e];
    }
    #pragma unroll
    for (int t=0;t<LP;t++){
      int qc = PROJ0+t;
      Qb[(qc>>4)*QTF_C + (qc&15)*32] = f2bs(dots[t]*(1.f/E_));
    }
  }
}

__device__ __forceinline__ void mid_base(int blk,
                       const float* conceptOut, const float* objOut,
                       const unsigned short* awFrag,
                       unsigned short* AoptC, unsigned short* AoptO){
  int n0 = blk * 64;
  int tid = threadIdx.x;
  int w = tid >> 6, l = tid & 63, quad = l >> 4, lq = l & 15;
  int n = n0 + w*16 + lq;
  const float* src = (n < NC) ? (conceptOut + (size_t)n*E_) : (objOut + (size_t)(n-NC)*E_);
  f32x4 acc[16];
  #pragma unroll
  for (int m=0;m<16;m++) acc[m] = (f32x4){0.f,0.f,0.f,0.f};
  #pragma unroll
  for (int kc=0;kc<2;kc++){
    s16x8 bfr;
    #pragma unroll
    for (int j=0;j<8;j++) bfr[j] = (short)f2bs(src[kc*32 + quad*8 + j]);
    const unsigned short* ap = awFrag + ((size_t)(kc*16)*64 + l)*8;
    #pragma unroll
    for (int m=0;m<16;m++){
      s16x8 af = *(const s16x8*)(ap + (size_t)m*64*8);
      acc[m] = __builtin_amdgcn_mfma_f32_16x16x32_bf16(af, bfr, acc[m], 0, 0, 0);
    }
  }
  int nl = n & 31;
  if (n < NC){
    int nch = n >> 5;
    #pragma unroll
    for (int m=0;m<16;m++){
      #pragma unroll
      for (int r=0;r<4;r++)
        AoptC[(size_t)(m*128 + nch)*512 + (quad*4+r)*32 + nl] = f2bs(acc[m][r]);
    }
  } else {
    int no = n - NC; int bb = no >> 7; int oc = (no & 127) >> 5;
    #pragma unroll
    for (int m=0;m<16;m++){
      #pragma unroll
      for (int r=0;r<4;r++)
        AoptO[(size_t)((bb*16 + m)*4 + oc)*512 + (quad*4+r)*32 + nl] = f2bs(acc[m][r]);
    }
  }
}

__device__ __forceinline__ void mid_qsumfin(int b, const float* conceptOut, const int* args,
                                            float* qsum){
  int tid = threadIdx.x;
  if (tid >= 64) return;
  float* acc = qsum + 640;
  const float* csumIn    = acc + 16;
  const float* csumOut   = acc + 80;
  const float* objsumIn  = acc + 144;
  const float* objsumOut = acc + 656;
  if (tid == 0) qsum[b*QC] = (float)NN;
  qsum[b*QC + 1 + tid] = csumIn[tid] + objsumIn[b*64+tid];
  if (tid < 3) qsum[b*QC + 77 + tid] = 0.f;
  float cot = csumOut[tid] + objsumOut[b*64+tid];
  for (int t=0;t<LP;t++){
    float av = conceptOut[args[b*LP+t]*E_ + tid];
    float r = cot * av;
    #pragma unroll
    for (int off=32; off>0; off>>=1) r += __shfl_down(r, off, 64);
    if (tid == 0) qsum[b*QC + PROJ0 + t] = r * (1.f/E_);
  }
}

__global__ __launch_bounds__(256) void k_mid(
    const float* conceptIn, const float* conceptOut,
    const float* meta_init, const float* mw1, const float* mb1, const float* mw2, const float* mb2,
    const float* aw1, const float* ab1, const int* ops, const int* args,
    const float* objIn, const float* objOut, const unsigned short* awFrag,
    float* metaAll, float* metaH, unsigned short* QTf, float* qsum,
    unsigned short* AoptC, unsigned short* AoptO){
  __shared__ __align__(16) char smem[133888];
  int mb = blockIdx.x;
  if (mb < 8)
    mid_meta(smem, mb, conceptOut, meta_init, mw1, mb1, mw2, mb2, aw1, ab1, ops, args, metaAll, metaH);
  else if (mb < 144)
    mid_qt(smem, mb-8, conceptIn, conceptOut, args, objIn, objOut, QTf);
  else if (mb < 224)
    mid_base(mb-144, conceptOut, objOut, awFrag, AoptC, AoptO);
  else
    mid_qsumfin(mb-224, conceptOut, args, qsum);
}

// ---------------- k_T (MFMA v6): single-wave blocks, kh 8-way K-split, no LDS/barriers ----------------
__global__ __launch_bounds__(64) void k_T(const unsigned short* AoptC, const unsigned short* AoptO,
                                          const unsigned short* QTf, const float* metaH,
                                          unsigned* TB){
  int bid = blockIdx.x;
  int kh = bid & 7; int ht = (bid >> 3) & 3; int bt = bid >> 5; int b = bt / LP;
  int l = threadIdx.x, quad = l >> 4, lq = l & 15;
  int off = lq*32 + quad*8;
  int start = (kh < 4) ? (kh*17) : (68 + (kh-4)*16);
  int count = (kh < 4) ? 17 : 16;
  float mh[4];
  #pragma unroll
  for (int s=0;s<4;s++) mh[s] = metaH[(size_t)bt*H_ + ht*64 + s*16 + lq];
  f32x4 acc[4][5];
  #pragma unroll
  for (int s=0;s<4;s++){
    #pragma unroll
    for (int c=0;c<5;c++) acc[s][c] = (f32x4){0.f,0.f,0.f,0.f};
  }
  const unsigned short* QTb = QTf + (size_t)b*QTF_B + off;
  const unsigned short* AC  = AoptC + (size_t)(ht*4)*65536 + off;       // 65536 = 128*512
  const unsigned short* AO  = AoptO + (size_t)(b*16 + ht*4)*2048 + off; // 2048 = 4*512
  for (int it=0; it<count; it++){
    int nchunk = start + it;
    U8 bfr[5];
    #pragma unroll
    for (int c=0;c<5;c++)
      bfr[c].v = *(const s16x8*)(QTb + (size_t)c*QTF_C + (size_t)nchunk*512);
    bool isC = (nchunk < 128);
    #pragma unroll
    for (int s=0;s<4;s++){
      U8 a;
      a.v = isC ? *(const s16x8*)(AC + (size_t)s*65536 + (size_t)nchunk*512)
                : *(const s16x8*)(AO + (size_t)s*2048 + (size_t)(nchunk-128)*512);
      float mhs = mh[s];
      U8 af;
      #pragma unroll
      for (int d=0;d<4;d++){
        unsigned wv = a.u[d];
        float lo = fmaxf(__uint_as_float(wv << 16) + mhs, 0.f);
        float hi = fmaxf(__uint_as_float(wv & 0xffff0000u) + mhs, 0.f);
        af.u[d] = __builtin_amdgcn_perm(__float_as_uint(hi), __float_as_uint(lo), 0x07060302u);
      }
      #pragma unroll
      for (int c=0;c<5;c++)
        acc[s][c] = __builtin_amdgcn_mfma_f32_16x16x32_bf16(af.v, bfr[c].v, acc[s][c], 0, 0, 0);
    }
  }
  unsigned* Tp = TB + (size_t)kh*TB_P + ((size_t)bt*4 + ht)*2560;
  #pragma unroll
  for (int s=0;s<4;s++){
    #pragma unroll
    for (int c=0;c<5;c++){
      uint2 v;
      v.x = pack2(acc[s][c][0], acc[s][c][1]);
      v.y = pack2(acc[s][c][2], acc[s][c][3]);
      *(uint2*)(Tp + (s*5+c)*128 + l*2) = v;
    }
  }
}

// ---------------- k_U v3: K-split x2; sums 8 bf16 TB partials during staging ----------------
__global__ __launch_bounds__(256) void k_U(const unsigned* TB,
                                           const float* w2, const float* b2v,
                                           const float* qsum, float* Ut0, float* Ut1){
  __shared__ float Wt[128*64];
  __shared__ float Tt[128*81];
  int bid = blockIdx.x;
  int kq = bid & 1; int bt = bid >> 1; int b = bt / LP;
  int tid = threadIdx.x;
  for (int i=tid; i<8192; i+=256){
    int hl = i >> 6, e = i & 63;
    Wt[i] = w2[(kq*128 + hl)*E_ + e];
  }
  #pragma unroll
  for (int half=0; half<2; half++){
    const unsigned* base = TB + ((size_t)bt*4 + kq*2 + half)*2560;
    for (int i2=tid; i2<2560; i2+=256){
      float lo = 0.f, hi = 0.f;
      #pragma unroll
      for (int p=0;p<8;p++){
        unsigned w = base[(size_t)p*TB_P + i2];
        lo += lo16f(w); hi += hi16f(w);
      }
      int idx = 2*i2;
      int sc = idx >> 8; int ll = (idx >> 2) & 63; int r = idx & 3;
      int s = sc/5, c = sc - s*5;
      int hl = half*64 + s*16 + ((ll>>4)<<2) + r;
      int qc = c*16 + (ll&15);
      Tt[hl*81 + qc]     = lo;
      Tt[(hl+1)*81 + qc] = hi;
    }
  }
  __syncthreads();
  int el = tid & 15, ql = tid >> 4;
  float acc[4][5];
  #pragma unroll
  for (int i=0;i<4;i++){
    #pragma unroll
    for (int j=0;j<5;j++) acc[i][j]=0.f;
  }
  #pragma unroll 4
  for (int kk=0; kk<128; kk++){
    float4 wv = *(const float4*)&Wt[kk*64 + el*4];
    float ww[4] = {wv.x, wv.y, wv.z, wv.w};
    const float* tp = &Tt[kk*81 + ql*5];
    #pragma unroll
    for (int j=0;j<5;j++){
      float tv = tp[j];
      #pragma unroll
      for (int i=0;i<4;i++) acc[i][j] = fmaf(ww[i], tv, acc[i][j]);
    }
  }
  const float invN = 1.f/NN;
  float* Up = (kq ? Ut1 : Ut0) + (size_t)bt*5120;
  if (kq == 0){
    float be[4], qv[5];
    #pragma unroll
    for (int i=0;i<4;i++) be[i] = b2v[el*4+i];
    #pragma unroll
    for (int j=0;j<5;j++) qv[j] = qsum[b*QC + ql*5+j];
    #pragma unroll
    for (int i=0;i<4;i++){
      #pragma unroll
      for (int j=0;j<5;j++)
        Up[(el*4+i)*QC + ql*5+j] = (acc[i][j] + be[i]*qv[j]) * invN;
    }
  } else {
    #pragma unroll
    for (int i=0;i<4;i++){
      #pragma unroll
      for (int j=0;j<5;j++)
        Up[(el*4+i)*QC + ql*5+j] = acc[i][j] * invN;
    }
  }
}

// ---------------- k_rec v3: MFMA per-step M = U_t @ C; padded LDS ----------------
__global__ __launch_bounds__(256) void k_rec(const float* Ut0, const float* Ut1, const float* metaAll,
                                             const int* ops, const float* att_init, float* Cm){
  __shared__ float C[QC*65];
  __shared__ float Ul[2][64*81];
  int b = blockIdx.x, tid = threadIdx.x;
  int w = tid >> 6, l = tid & 63, quad = l >> 4, lq = l & 15;
  for (int i=tid;i<QC*65;i+=256) C[i] = 0.f;
  if (tid < A_) C[tid] = att_init[tid];
  {
    const float* U0 = Ut0 + (size_t)(b*LP)*5120;
    const float* U1 = Ut1 + (size_t)(b*LP)*5120;
    #pragma unroll
    for (int k=0;k<5;k++){
      int i = tid*4 + k*1024;
      float4 v0 = *(const float4*)&U0[i];
      float4 v1 = *(const float4*)&U1[i];
      int r = i/80, c = i%80;
      Ul[0][r*81+c]   = v0.x+v1.x; Ul[0][r*81+c+1] = v0.y+v1.y;
      Ul[0][r*81+c+2] = v0.z+v1.z; Ul[0][r*81+c+3] = v0.w+v1.w;
    }
  }
  __syncthreads();
  for (int t=0;t<LP;t++){
    float4 rv0[5], rv1[5];
    if (t < LP-1){
      const float* U0 = Ut0 + (size_t)(b*LP+t+1)*5120;
      const float* U1 = Ut1 + (size_t)(b*LP+t+1)*5120;
      #pragma unroll
      for (int k=0;k<5;k++){
        rv0[k] = *(const float4*)&U0[tid*4 + k*1024];
        rv1[k] = *(const float4*)&U1[tid*4 + k*1024];
      }
    }
    const float* Uc = Ul[t&1];
    U8 af[3][4];
    #pragma unroll
    for (int k0t=0;k0t<3;k0t++){
      #pragma unroll
      for (int s=0;s<4;s++){
        int e = s*16 + lq;
        int qb = k0t*32 + quad*8;
        float v[8];
        #pragma unroll
        for (int j=0;j<8;j++){
          int qc = qb + j;
          v[j] = (qc < QC) ? Uc[e*81 + qc] : 0.f;
        }
        #pragma unroll
        for (int d=0;d<4;d++) af[k0t][s].u[d] = pack2(v[2*d], v[2*d+1]);
      }
    }
    U8 bf[3];
    #pragma unroll
    for (int k0t=0;k0t<3;k0t++){
      int kb = k0t*32 + quad*8;
      float v[8];
      #pragma unroll
      for (int j=0;j<8;j++){
        int k = kb + j;
        v[j] = (k < QC) ? C[k*65 + w*16 + lq] : 0.f;
      }
      #pragma unroll
      for (int d=0;d<4;d++) bf[k0t].u[d] = pack2(v[2*d], v[2*d+1]);
    }
    f32x4 acc[4];
    #pragma unroll
    for (int s=0;s<4;s++){
      acc[s] = (f32x4){0.f,0.f,0.f,0.f};
      #pragma unroll
      for (int k0t=0;k0t<3;k0t++)
        acc[s] = __builtin_amdgcn_mfma_f32_16x16x32_bf16(af[k0t][s].v, bf[k0t].v, acc[s], 0, 0, 0);
    }
    int op = ops[b*LP + t];
    float tr  = (op==2) ? 1.f : 0.f;
    float ins = (op==1) ? 1.f : 0.f;
    __syncthreads();
    #pragma unroll
    for (int s=0;s<4;s++){
      #pragma unroll
      for (int r=0;r<4;r++){
        int e = s*16 + quad*4 + r;
        C[(1+e)*65 + w*16 + lq] += tr*acc[s][r];
      }
    }
    if (tid < A_) C[(PROJ0+t)*65 + tid] += ins*metaAll[(b*LP+t)*A_ + tid];
    if (t < LP-1){
      float* Un = Ul[(t+1)&1];
      #pragma unroll
      for (int k=0;k<5;k++){
        int i = tid*4 + k*1024;
        int r = i/80, c = i%80;
        Un[r*81+c]   = rv0[k].x+rv1[k].x; Un[r*81+c+1] = rv0[k].y+rv1[k].y;
        Un[r*81+c+2] = rv0[k].z+rv1[k].z; Un[r*81+c+3] = rv0[k].w+rv1[k].w;
      }
    }
    __syncthreads();
  }
  for (int i=tid;i<QC*A_;i+=256) Cm[b*QC*A_ + i] = C[(i>>6)*65 + (i&63)];
}

// ---------------- k_out: ol + esum + (last block per b) log-softmax finalize ----------------
__global__ __launch_bounds__(128) void k_out(const unsigned short* QTf, const float* Cm,
                                             float* ol, float* esum, const int* flag, void* out){
  __shared__ float C[QC*A_];
  __shared__ float wsum[2];
  __shared__ bool last;
  unsigned* cnt = (unsigned*)(esum + 8);
  int b = blockIdx.x / 33, rem = blockIdx.x % 33;
  int tid = threadIdx.x;
  for (int i=tid;i<QC*A_;i+=128) C[i] = Cm[b*QC*A_ + i];
  __syncthreads();
  int n = rem*128 + tid;
  float y[A_];
  #pragma unroll
  for (int a=0;a<A_;a++) y[a]=0.f;
  const unsigned short* Qb = QTf + (size_t)b*QTF_B + ((n>>5)*512 + (n&31));
  for (int j=0;j<QC;j++){
    float qvv = bs2f(Qb[(j>>4)*QTF_C + (j&15)*32]);
    const float* Cj = &C[j*A_];
    #pragma unroll
    for (int a=0;a<A_;a++) y[a] = fmaf(qvv, Cj[a], y[a]);
  }
  float s = 0.f;
  #pragma unroll
  for (int a=0;a<A_;a++) s = fmaf(y[a], y[a], s);
  float o = s * (1.f/A_);
  ol[(size_t)b*NN + n] = o;
  float contrib = expf(o);
  #pragma unroll
  for (int off=32; off>0; off>>=1) contrib += __shfl_down(contrib, off, 64);
  if ((tid & 63) == 0) wsum[tid>>6] = contrib;
  __syncthreads();
  if (tid == 0){
    atomicAdd(&esum[b], wsum[0]+wsum[1]);
    __threadfence();
    unsigned old = atomicAdd(&cnt[b], 1u);
    last = (old == 32u);
  }
  __syncthreads();
  if (last){
    __threadfence();                          // acquire: see other blocks' ol/esum
    float es = esum[b];
    float lsm = logf(es);
    const float* olb = ol + (size_t)b*NN;
    if (*flag){
      float* op_ = (float*)out + (size_t)b*NN;
      for (int i=tid;i<NN;i+=128) op_[i] = olb[i] - lsm;
    } else {
      bf16* op_ = (bf16*)out + (size_t)b*NN;
      for (int i=tid;i<NN;i+=128) op_[i] = __float2bfloat16(olb[i] - lsm);
    }
  }
}

extern "C" void kernel_launch(void* const* d_in, const int* in_sizes, int n_in,
                              void* d_out, int out_size, void* d_ws, size_t ws_size,
                              hipStream_t stream) {
  (void)in_sizes; (void)n_in; (void)out_size; (void)ws_size;
  const int* ops  = (const int*)d_in[17];
  const int* args = (const int*)d_in[18];
  const int* gtc  = (const int*)d_in[19];
  const int* gta  = (const int*)d_in[20];

  float* ws = (float*)d_ws;
  int* flag = (int*)ws;
  float* W  = ws + 16;

  const float* conceptIn  = W + 65536;
  const float* conceptOut = W + 327680;
  const float* meta_init  = W + 589824;
  const float* att_init   = W + 589888;
  const float* aw1        = W + 589952;
  const float* ab1        = W + 622720;
  const float* aw2        = W + 622976;
  const float* ab2        = W + 639360;
  const float* mw1        = W + 639424;
  const float* mb1        = W + 672192;
  const float* mw2        = W + 672448;
  const float* mb2        = W + 688832;

  constexpr size_t OFF_OBJIN   = 16 + TOT_IN;            // 688912
  constexpr size_t OFF_OBJOUT  = OFF_OBJIN  + 65536;     // 754448
  constexpr size_t OFF_METAALL = OFF_OBJOUT + 65536;     // 819984
  constexpr size_t OFF_METAH   = OFF_METAALL + 6144;     // 826128
  constexpr size_t OFF_QSUM    = OFF_METAH  + 24576;     // 850704
  constexpr size_t OFF_ESUM    = OFF_QSUM   + 640;       // 851344  (esum8|cnt8|csi64|cso64|osi512|oso512)
  constexpr size_t OFF_UT0     = OFF_ESUM   + 1168;      // 852512
  constexpr size_t OFF_UT1     = OFF_UT0    + 491520;    // 1344032
  constexpr size_t OFF_CM      = OFF_UT1    + 491520;    // 1835552
  constexpr size_t OFF_OL      = OFF_CM     + 40960;     // 1876512
  constexpr size_t OFF_QTF     = OFF_OL     + 33792;     // 1910304
  constexpr size_t OFF_AOPTC   = OFF_QTF    + 1351680;   // 3261984
  constexpr size_t OFF_AOPTO   = OFF_AOPTC  + 524288;    // 3786272
  constexpr size_t OFF_AWF     = OFF_AOPTO  + 131072;    // 3917344
  constexpr size_t OFF_TB      = OFF_AWF    + 8192;      // 3925536, 8 x 983040 dwords
  // end = OFF_TB + 7864320 = 11,789,856 floats ~= 47.2 MB

  float* objIn   = ws + OFF_OBJIN;
  float* objOut  = ws + OFF_OBJOUT;
  float* metaAll = ws + OFF_METAALL;
  float* metaH   = ws + OFF_METAH;
  float* qsum    = ws + OFF_QSUM;
  float* esum    = ws + OFF_ESUM;
  float* Ut0     = ws + OFF_UT0;
  float* Ut1     = ws + OFF_UT1;
  float* Cm      = ws + OFF_CM;
  float* ol      = ws + OFF_OL;
  unsigned short* QTf    = (unsigned short*)(ws + OFF_QTF);
  unsigned short* AoptC  = (unsigned short*)(ws + OFF_AOPTC);
  unsigned short* AoptO  = (unsigned short*)(ws + OFF_AOPTO);
  unsigned short* awFrag = (unsigned short*)(ws + OFF_AWF);
  unsigned* TB           = (unsigned*)(ws + OFF_TB);

  // zero esum/cnt/csum/objsum accumulators (4.7 KB)
  hipMemsetAsync(esum, 0, 1168*sizeof(float), stream);

  Ptr16 ps;
  const int src_idx[16] = {0,1,2,3,4,5,6,8,9,10,11,12,13,14,15,16};
  for (int i=0;i<16;i++) ps.p[i] = d_in[src_idx[i]];

  k_prep<<<3043, 256, 0, stream>>>(ps, flag, W, awFrag, gtc, gta, objIn, objOut, qsum);
  k_mid <<<232, 256, 0, stream>>>(conceptIn, conceptOut, meta_init, mw1, mb1, mw2, mb2,
                                  aw1, ab1, ops, args, objIn, objOut, awFrag,
                                  metaAll, metaH, QTf, qsum, AoptC, AoptO);
  k_T   <<<B_*LP*4*8, 64, 0, stream>>>(AoptC, AoptO, QTf, metaH, TB);
  k_U   <<<B_*LP*2, 256, 0, stream>>>(TB, aw2, ab2, qsum, Ut0, Ut1);
  k_rec <<<B_, 256, 0, stream>>>(Ut0, Ut1, metaAll, ops, att_init, Cm);
  k_out <<<B_*33, 128, 0, stream>>>(QTf, Cm, ol, esum, flag, d_out);
}